// Round 10
// baseline (769.774 us; speedup 1.0000x reference)
//
#include <hip/hip_runtime.h>

#define N_ENT 200000
#define N_USR 100000
#define NT3   700000      // N_ENT*3 virt-segments + N_USR user segments
#define UKEY0 600000      // first user segment key
#define DIM 64
#define NE 1500000
#define NI_ 1000000
#define NTE 2500000       // NE + NI_
#define NREL1 10
#define NVIRT 3
#define EPSF 1e-12f
#define SCAN_B 1024
#define RE 6              // cached rows per (entity,virt) segment (Poisson ~2.5)
#define RU 12             // cached rows per user segment (Poisson ~10)
#define NBUCK 64
#define NPERM (N_ENT + N_USR)            // 300000
#define NPB   ((NPERM + 255) / 256)      // 1172 histogram blocks

// ---------- float4 helpers ----------
__device__ __forceinline__ float4 f4_zero() { return make_float4(0.f, 0.f, 0.f, 0.f); }
__device__ __forceinline__ float4 f4_add(float4 a, float4 b) {
    return make_float4(a.x + b.x, a.y + b.y, a.z + b.z, a.w + b.w);
}
__device__ __forceinline__ float4 f4_scale(float s, float4 a) {
    return make_float4(s * a.x, s * a.y, s * a.z, s * a.w);
}
__device__ __forceinline__ float4 f4_fma(float s, float4 a, float4 b) {
    return make_float4(fmaf(s, a.x, b.x), fmaf(s, a.y, b.y), fmaf(s, a.z, b.z), fmaf(s, a.w, b.w));
}
__device__ __forceinline__ float f4_dot(float4 a, float4 b) {
    return a.x * b.x + a.y * b.y + a.z * b.z + a.w * b.w;
}

// 16-lane all-lanes sum via DPP (VALU pipe, no lgkmcnt).
__device__ __forceinline__ float red16(float v) {
    int x;
    x = __builtin_amdgcn_update_dpp(0, __float_as_int(v), 0xB1, 0xF, 0xF, true);  // quad_perm [1,0,3,2]
    v += __int_as_float(x);
    x = __builtin_amdgcn_update_dpp(0, __float_as_int(v), 0x4E, 0xF, 0xF, true);  // quad_perm [2,3,0,1]
    v += __int_as_float(x);
    x = __builtin_amdgcn_update_dpp(0, __float_as_int(v), 0x124, 0xF, 0xF, true); // row_ror:4
    v += __int_as_float(x);
    x = __builtin_amdgcn_update_dpp(0, __float_as_int(v), 0x128, 0xF, 0xF, true); // row_ror:8
    v += __int_as_float(x);
    return v;
}

__device__ __forceinline__ float4 squash4(float4 u, float sq) {
    float n = sqrtf(sq);
    float s = sq / ((sq + 1.f) * fmaxf(n, EPSF));
    return f4_scale(s, u);
}

// in-block relation->virt remap: 10 thr x 3 dot64
__device__ __forceinline__ void block_remap(const float* __restrict__ rw,
                                            const float* __restrict__ lat,
                                            int* sremap) {
    int t = threadIdx.x;
    if (t < NREL1) {
        float best = -3.4e38f; int bi = 0;
        for (int j = 0; j < NVIRT; j++) {
            float s = 0.f;
            for (int d = 0; d < DIM; d++) s += rw[t * DIM + d] * lat[j * DIM + d];
            if (s > best) { best = s; bi = j; }
        }
        sremap[t] = bi;
    }
    __syncthreads();
}

// ---------- combined CSR build ----------
// count also records each element's within-segment arrival rank -> scatter needs no atomics.
__global__ void k_count_all(const int* __restrict__ head, const int* __restrict__ etype,
                            const float* __restrict__ rw, const float* __restrict__ lat,
                            const int* __restrict__ uidx, int* __restrict__ cnt,
                            int* __restrict__ rank) {
    __shared__ int sremap[NREL1];
    block_remap(rw, lat, sremap);
    int i = blockIdx.x * blockDim.x + threadIdx.x;
    if (i < NE) {
        int key = head[i] * 3 + sremap[etype[i] - 1];
        rank[i] = atomicAdd(&cnt[key], 1);
    } else if (i < NTE) {
        rank[i] = atomicAdd(&cnt[UKEY0 + uidx[i - NE]], 1);
    }
}

__global__ void k_scan1(const int* __restrict__ in, int* __restrict__ excl,
                        int* __restrict__ bsum, int n) {
    __shared__ int s[SCAN_B];
    int tid = threadIdx.x, gid = blockIdx.x * SCAN_B + tid;
    int v = (gid < n) ? in[gid] : 0;
    s[tid] = v; __syncthreads();
    for (int off = 1; off < SCAN_B; off <<= 1) {
        int t = 0;
        if (tid >= off) t = s[tid - off];
        __syncthreads();
        s[tid] += t;
        __syncthreads();
    }
    if (gid < n) excl[gid] = s[tid] - v;
    if (tid == SCAN_B - 1) bsum[blockIdx.x] = s[tid];
}

// merged scan2+scan3: each block tree-reduces its own prefix of raw block sums.
__global__ void k_scan23(const int* __restrict__ excl, const int* __restrict__ bsum,
                         const int* __restrict__ cnt, int* __restrict__ rp,
                         int n, int nb) {
    __shared__ int s[SCAN_B];
    int tid = threadIdx.x;
    int v = (tid < nb && tid < (int)blockIdx.x) ? bsum[tid] : 0;
    s[tid] = v;
    __syncthreads();
    for (int off = SCAN_B / 2; off > 0; off >>= 1) {
        if (tid < off) s[tid] += s[tid + off];
        __syncthreads();
    }
    int prefix = s[0];
    int gid = blockIdx.x * SCAN_B + tid;
    if (gid < n) {
        int val = excl[gid] + prefix;
        rp[gid] = val;
        if (gid == n - 1) rp[n] = val + cnt[gid];
    }
}

// atomic-free scatter: pos = rp[key] + precomputed rank
__global__ void k_scatter_all(const int* __restrict__ head, const int* __restrict__ tail,
                              const int* __restrict__ etype,
                              const float* __restrict__ rw, const float* __restrict__ lat,
                              const int* __restrict__ uidx, const int* __restrict__ iidx,
                              const int* __restrict__ rp, const int* __restrict__ rank,
                              int* __restrict__ sorted) {
    __shared__ int sremap[NREL1];
    block_remap(rw, lat, sremap);
    int i = blockIdx.x * blockDim.x + threadIdx.x;
    if (i < NE) {
        int key = head[i] * 3 + sremap[etype[i] - 1];
        sorted[rp[key] + rank[i]] = tail[i];
    } else if (i < NTE) {
        int j = i - NE;
        sorted[rp[UKEY0 + uidx[j]] + rank[i]] = iidx[j];
    }
}

// ---------- degree-sort permutation via block-local counting sort ----------
__device__ __forceinline__ int perm_bucket(const int* __restrict__ rp, int i) {
    if (i < N_ENT) {
        int d = rp[i * 3 + 3] - rp[i * 3];
        return (d < NBUCK) ? d : (NBUCK - 1);
    }
    int u = i - N_ENT;
    int d = rp[UKEY0 + u + 1] - rp[UKEY0 + u];
    return NBUCK + ((d < NBUCK) ? d : (NBUCK - 1));
}

// stage 1: per-block LDS histogram -> bh[bucket*NPB + block]
__global__ void k_histL(const int* __restrict__ rp, int* __restrict__ bh) {
    __shared__ int h[2 * NBUCK];
    int t = threadIdx.x;
    if (t < 2 * NBUCK) h[t] = 0;
    __syncthreads();
    int i = blockIdx.x * 256 + t;
    if (i < NPERM) atomicAdd(&h[perm_bucket(rp, i)], 1);
    __syncthreads();
    if (t < 2 * NBUCK) bh[t * NPB + blockIdx.x] = h[t];
}

// stage 2: one workgroup per bucket; exclusive scan of bh[b][0..NPB) + total
__global__ void k_histscan(int* __restrict__ bh, int* __restrict__ bt) {
    __shared__ int s[SCAN_B];
    int b = blockIdx.x, t = threadIdx.x;
    int base = b * NPB;
    int i0 = 2 * t, i1 = 2 * t + 1;
    int a0 = (i0 < NPB) ? bh[base + i0] : 0;
    int a1 = (i1 < NPB) ? bh[base + i1] : 0;
    int pair = a0 + a1;
    s[t] = pair; __syncthreads();
    for (int off = 1; off < SCAN_B; off <<= 1) {
        int v = 0;
        if (t >= off) v = s[t - off];
        __syncthreads();
        s[t] += v;
        __syncthreads();
    }
    int exclPair = s[t] - pair;
    if (i0 < NPB) bh[base + i0] = exclPair;
    if (i1 < NPB) bh[base + i1] = exclPair + a0;
    if (t == SCAN_B - 1) bt[b] = s[t];
}

// stage 3 (folded): scatter; each block locally scans bucket totals first.
__global__ void k_permb(const int* __restrict__ rp, const int* __restrict__ bh,
                        const int* __restrict__ bt,
                        int* __restrict__ permE, int* __restrict__ permU) {
    __shared__ int sb[2 * NBUCK];
    __shared__ int cur[2 * NBUCK];
    int t = threadIdx.x;
    int v0 = 0;
    if (t < 2 * NBUCK) { v0 = bt[t]; sb[t] = v0; cur[t] = 0; }
    __syncthreads();
    for (int off = 1; off < NBUCK; off <<= 1) {
        int x = 0;
        if (t < 2 * NBUCK && t >= off && ((t - off) >> 6) == (t >> 6)) x = sb[t - off];
        __syncthreads();
        if (t < 2 * NBUCK) sb[t] += x;
        __syncthreads();
    }
    if (t < 2 * NBUCK) sb[t] -= v0;          // exclusive base within E/U half
    __syncthreads();
    int i = blockIdx.x * 256 + t;
    if (i < NPERM) {
        int b = perm_bucket(rp, i);
        int l = atomicAdd(&cur[b], 1);
        int pos = sb[b] + bh[b * NPB + blockIdx.x] + l;
        if (i < N_ENT) permE[pos] = i;
        else permU[pos] = i - N_ENT;
    }
}

// ---------- merged per-hop LWS: per-virt sequential entity path + user path ----------
#define NBLK_E (N_ENT / 16)   // 12500
#define NBLK_U (N_USR / 16)   // 6250

__global__ __launch_bounds__(256, 5) void k_hop(
    const float* __restrict__ ent, const float* __restrict__ usr,
    const int* __restrict__ rp, const int* __restrict__ sorted,
    const int* __restrict__ permE, const int* __restrict__ permU,
    const float* __restrict__ aw, int hop,
    float* __restrict__ ent_next, float* __restrict__ usr_next,
    int do_store, int first,
    float* __restrict__ outE, float* __restrict__ outU)
{
    int lane = threadIdx.x & 15;
    const float4* entv = (const float4*)ent;

    if (blockIdx.x < NBLK_E) {
        // ================= entity path: 3 independent per-virt LWS =================
        int g = permE[blockIdx.x * 16 + (threadIdx.x >> 4)];
        float4 eh = entv[g * 16 + lane];
        float4 agg = f4_zero();

        // softmax(agg_w[hop]) inline
        float a0 = aw[hop * 3 + 0], a1 = aw[hop * 3 + 1], a2 = aw[hop * 3 + 2];
        float m = fmaxf(a0, fmaxf(a1, a2));
        float e0 = expf(a0 - m), e1 = expf(a1 - m), e2 = expf(a2 - m);
        float esum = e0 + e1 + e2;
        float w0 = e0 / esum, w1 = e1 / esum, w2 = e2 / esum;

        // hoisted segment bounds for all 3 virts
        int b3 = g * 3;
        int s0 = rp[b3], s1 = rp[b3 + 1], s2 = rp[b3 + 2], s3 = rp[b3 + 3];
        int dg0 = s1 - s0, dg1 = s2 - s1, dg2 = s3 - s2;

        #pragma unroll
        for (int v = 0; v < NVIRT; v++) {
            int s   = (v == 0) ? s0   : (v == 1) ? s1   : s2;
            int deg = (v == 0) ? dg0  : (v == 1) ? dg1  : dg2;
            float w = (v == 0) ? w0   : (v == 1) ? w1   : w2;
            float inv = 1.f / fmaxf((float)deg, 1.f);

            float4 xc[RE];
            // ---- iter 0 (+ cache fill); direct uniform index loads (16 lanes same addr
            // -> single broadcast fetch; removes ds_bpermute from the address chain)
            float4 acc = f4_zero();
            #pragma unroll
            for (int r = 0; r < RE; r++) {
                if (r < deg) {
                    int p = sorted[s + r];
                    float4 x = entv[p * 16 + lane];
                    xc[r] = x;
                    acc = f4_add(acc, x);
                }
            }
            for (int r = RE; r < deg; r++) {
                int p = sorted[s + r];
                acc = f4_add(acc, entv[p * 16 + lane]);
            }
            float4 u = f4_scale(inv, acc);
            float sq = red16(f4_dot(u, u));
            float4 u1 = f4_add(squash4(u, sq), eh);

            // ---- iter 1: d1 = dot(u1,x); cached rows keep d1 in registers
            float4 acc1 = f4_zero();
            float d1c[RE];
            float d1me = 0.f;
            #pragma unroll
            for (int r = 0; r < RE; r++) {
                if (r < deg) {
                    float4 x = xc[r];
                    float d1 = red16(f4_dot(u1, x));
                    d1c[r] = d1;
                    acc1 = f4_fma(d1, x, acc1);
                }
            }
            for (int r = RE; r < deg; r++) {
                int p = sorted[s + r];
                float4 x = entv[p * 16 + lane];
                float d1 = red16(f4_dot(u1, x));
                if (lane == r) d1me = d1;      // only lanes 0..15, so only r<16 captured
                acc1 = f4_fma(d1, x, acc1);
            }
            u = f4_scale(inv, acc1);
            sq = red16(f4_dot(u, u));
            float4 u2 = f4_add(squash4(u, sq), eh);

            // ---- iter 2: scale = d1^2 * d2
            float4 acc2 = f4_zero();
            #pragma unroll
            for (int r = 0; r < RE; r++) {
                if (r < deg) {
                    float4 x = xc[r];
                    float d2 = red16(f4_dot(u2, x));
                    float d1 = d1c[r];
                    acc2 = f4_fma(d1 * d1 * d2, x, acc2);
                }
            }
            for (int r = RE; r < deg; r++) {
                int p = sorted[s + r];
                float4 x = entv[p * 16 + lane];
                float d2 = red16(f4_dot(u2, x));
                float d1 = (r < 16) ? __shfl(d1me, r, 16) : red16(f4_dot(u1, x));
                acc2 = f4_fma(d1 * d1 * d2, x, acc2);
            }
            agg = f4_fma(w * inv, acc2, agg);
        }
        // Σ_v w_v*(inv_v*acc_v + eh) = agg + eh  (Σw = 1)
        agg = f4_add(agg, eh);
        float sq = red16(f4_dot(agg, agg));
        float nn = sqrtf(sq);
        float4 en = f4_scale(1.f / fmaxf(nn, EPSF), agg);
        if (do_store) ((float4*)ent_next)[g * 16 + lane] = en;
        float4* outv = (float4*)outE;
        float4 base = first ? eh : outv[g * 16 + lane];
        outv[g * 16 + lane] = f4_add(base, en);
    } else {
        // ================= user path (register-cached rows) ======
        int gu = permU[(blockIdx.x - NBLK_E) * 16 + (threadIdx.x >> 4)];
        int s = rp[UKEY0 + gu], e = rp[UKEY0 + gu + 1];
        int deg = e - s;
        const float4* usrv = (const float4*)usr;
        float4 uh = usrv[gu * 16 + lane];
        float inv = 1.f / fmaxf((float)deg, 1.f);

        float4 xc[RU];
        float4 acc = f4_zero();
        // iter 0 + cache fill (direct uniform index loads)
        #pragma unroll
        for (int r = 0; r < RU; r++) {
            if (r < deg) {
                int p = sorted[s + r];
                float4 x = entv[p * 16 + lane];
                xc[r] = x;
                acc = f4_add(acc, x);
            }
        }
        for (int r = RU; r < deg; r++) {
            int p = sorted[s + r];
            acc = f4_add(acc, entv[p * 16 + lane]);
        }
        float4 u = f4_scale(inv, acc);
        float sq = red16(f4_dot(u, u));
        float4 u1 = f4_add(squash4(u, sq), uh);

        // iter 1: scale = dot(u1, x)
        acc = f4_zero();
        #pragma unroll
        for (int r = 0; r < RU; r++) {
            if (r < deg) {
                float4 x = xc[r];
                acc = f4_fma(red16(f4_dot(u1, x)), x, acc);
            }
        }
        for (int r = RU; r < deg; r++) {
            int p = sorted[s + r];
            float4 x = entv[p * 16 + lane];
            acc = f4_fma(red16(f4_dot(u1, x)), x, acc);
        }
        u = f4_scale(inv, acc);
        sq = red16(f4_dot(u, u));
        float4 u2 = f4_add(squash4(u, sq), uh);

        // iter 2: scale = dot(u2, x)
        acc = f4_zero();
        #pragma unroll
        for (int r = 0; r < RU; r++) {
            if (r < deg) {
                float4 x = xc[r];
                acc = f4_fma(red16(f4_dot(u2, x)), x, acc);
            }
        }
        for (int r = RU; r < deg; r++) {
            int p = sorted[s + r];
            float4 x = entv[p * 16 + lane];
            acc = f4_fma(red16(f4_dot(u2, x)), x, acc);
        }
        float4 u3 = f4_add(f4_scale(inv, acc), uh);
        sq = red16(f4_dot(u3, u3));
        float nn = sqrtf(sq);
        float4 un = f4_scale(1.f / fmaxf(nn, EPSF), u3);
        if (do_store) ((float4*)usr_next)[gu * 16 + lane] = un;
        float4* outv = (float4*)outU;
        float4 base = first ? uh : outv[gu * 16 + lane];
        outv[gu * 16 + lane] = f4_add(base, un);
    }
}

// ---------- launch ----------
extern "C" void kernel_launch(void* const* d_in, const int* in_sizes, int n_in,
                              void* d_out, int out_size, void* d_ws, size_t ws_size,
                              hipStream_t stream)
{
    const float* entity_emb = (const float*)d_in[0];
    const float* user_emb   = (const float*)d_in[1];
    const float* latent     = (const float*)d_in[2];
    const float* rel_w      = (const float*)d_in[3];
    const float* agg_w      = (const float*)d_in[4];
    const int* edge_index   = (const int*)d_in[5];
    const int* edge_type    = (const int*)d_in[6];
    const int* user_index   = (const int*)d_in[7];
    const int* item_index   = (const int*)d_in[8];
    float* out = (float*)d_out;

    char* ws = (char*)d_ws;
    size_t off = 0;
    auto alloc = [&](size_t bytes) -> void* {
        void* p = ws + off;
        off += (bytes + 255) / 256 * 256;
        return p;
    };
    float* entA  = (float*)alloc((size_t)N_ENT * DIM * 4);
    float* usrA  = (float*)alloc((size_t)N_USR * DIM * 4);
    int* cnt     = (int*)alloc((size_t)NT3 * 4);
    int* rp      = (int*)alloc((size_t)(NT3 + 1) * 4);
    int* excl    = (int*)alloc((size_t)NT3 * 4);
    int* bsum    = (int*)alloc(1024 * 4);
    int* sorted  = (int*)alloc((size_t)NTE * 4);
    int* rank    = (int*)alloc((size_t)NTE * 4);
    int* bh      = (int*)alloc((size_t)2 * NBUCK * NPB * 4);   // 600 KB
    int* bt      = (int*)alloc(2 * NBUCK * 4);
    int* permE   = (int*)alloc((size_t)N_ENT * 4);
    int* permU   = (int*)alloc((size_t)N_USR * 4);

    const int* head = edge_index;
    const int* tail = edge_index + NE;

    hipMemsetAsync(cnt, 0, (size_t)NT3 * 4, stream);

    k_count_all<<<(NTE + 255) / 256, 256, 0, stream>>>(
        head, edge_type, rel_w, latent, user_index, cnt, rank);

    int nb = (NT3 + SCAN_B - 1) / SCAN_B;   // 684 <= 1024
    k_scan1<<<nb, SCAN_B, 0, stream>>>(cnt, excl, bsum, NT3);
    k_scan23<<<nb, SCAN_B, 0, stream>>>(excl, bsum, cnt, rp, NT3, nb);

    k_scatter_all<<<(NTE + 255) / 256, 256, 0, stream>>>(
        head, tail, edge_type, rel_w, latent, user_index, item_index, rp, rank, sorted);

    // degree-sort permutation via block-local counting sort
    k_histL<<<NPB, 256, 0, stream>>>(rp, bh);
    k_histscan<<<2 * NBUCK, SCAN_B, 0, stream>>>(bh, bt);
    k_permb<<<NPB, 256, 0, stream>>>(rp, bh, bt, permE, permU);

    const float* ec = entity_emb;
    const float* uc = user_emb;
    for (int hop = 0; hop < 2; hop++) {
        int do_store = (hop == 0);
        int first = (hop == 0);
        k_hop<<<NBLK_E + NBLK_U, 256, 0, stream>>>(
            ec, uc, rp, sorted, permE, permU, agg_w, hop, entA, usrA, do_store, first,
            out, out + (size_t)N_ENT * DIM);
        ec = entA;
        uc = usrA;
    }
}

// Round 11
// 701.648 us; speedup vs baseline: 1.0971x; 1.0971x over previous
//
#include <hip/hip_runtime.h>

#define N_ENT 200000
#define N_USR 100000
#define NT3   700000      // N_ENT*3 virt-segments + N_USR user segments
#define UKEY0 600000      // first user segment key
#define DIM 64
#define NE 1500000
#define NI_ 1000000
#define NTE 2500000       // NE + NI_
#define NREL1 10
#define NVIRT 3
#define EPSF 1e-12f
#define SCAN_B 1024
#define RE 6              // cached rows per (entity,virt) segment (Poisson ~2.5)
#define RU 12             // cached rows per user segment (Poisson ~10)
#define NBUCK 64
#define NPERM (N_ENT + N_USR)            // 300000
#define NPB   ((NPERM + 255) / 256)      // 1172 histogram blocks

// ---------- float4 helpers ----------
__device__ __forceinline__ float4 f4_zero() { return make_float4(0.f, 0.f, 0.f, 0.f); }
__device__ __forceinline__ float4 f4_add(float4 a, float4 b) {
    return make_float4(a.x + b.x, a.y + b.y, a.z + b.z, a.w + b.w);
}
__device__ __forceinline__ float4 f4_scale(float s, float4 a) {
    return make_float4(s * a.x, s * a.y, s * a.z, s * a.w);
}
__device__ __forceinline__ float4 f4_fma(float s, float4 a, float4 b) {
    return make_float4(fmaf(s, a.x, b.x), fmaf(s, a.y, b.y), fmaf(s, a.z, b.z), fmaf(s, a.w, b.w));
}
__device__ __forceinline__ float f4_dot(float4 a, float4 b) {
    return a.x * b.x + a.y * b.y + a.z * b.z + a.w * b.w;
}

// 16-lane all-lanes sum via DPP (VALU pipe, no lgkmcnt).
__device__ __forceinline__ float red16(float v) {
    int x;
    x = __builtin_amdgcn_update_dpp(0, __float_as_int(v), 0xB1, 0xF, 0xF, true);  // quad_perm [1,0,3,2]
    v += __int_as_float(x);
    x = __builtin_amdgcn_update_dpp(0, __float_as_int(v), 0x4E, 0xF, 0xF, true);  // quad_perm [2,3,0,1]
    v += __int_as_float(x);
    x = __builtin_amdgcn_update_dpp(0, __float_as_int(v), 0x124, 0xF, 0xF, true); // row_ror:4
    v += __int_as_float(x);
    x = __builtin_amdgcn_update_dpp(0, __float_as_int(v), 0x128, 0xF, 0xF, true); // row_ror:8
    v += __int_as_float(x);
    return v;
}

__device__ __forceinline__ float4 squash4(float4 u, float sq) {
    float n = sqrtf(sq);
    float s = sq / ((sq + 1.f) * fmaxf(n, EPSF));
    return f4_scale(s, u);
}

// in-block relation->virt remap: 10 thr x 3 dot64
__device__ __forceinline__ void block_remap(const float* __restrict__ rw,
                                            const float* __restrict__ lat,
                                            int* sremap) {
    int t = threadIdx.x;
    if (t < NREL1) {
        float best = -3.4e38f; int bi = 0;
        for (int j = 0; j < NVIRT; j++) {
            float s = 0.f;
            for (int d = 0; d < DIM; d++) s += rw[t * DIM + d] * lat[j * DIM + d];
            if (s > best) { best = s; bi = j; }
        }
        sremap[t] = bi;
    }
    __syncthreads();
}

// ---------- combined CSR build ----------
// count also records each element's within-segment arrival rank -> scatter needs no atomics.
__global__ void k_count_all(const int* __restrict__ head, const int* __restrict__ etype,
                            const float* __restrict__ rw, const float* __restrict__ lat,
                            const int* __restrict__ uidx, int* __restrict__ cnt,
                            int* __restrict__ rank) {
    __shared__ int sremap[NREL1];
    block_remap(rw, lat, sremap);
    int i = blockIdx.x * blockDim.x + threadIdx.x;
    if (i < NE) {
        int key = head[i] * 3 + sremap[etype[i] - 1];
        rank[i] = atomicAdd(&cnt[key], 1);
    } else if (i < NTE) {
        rank[i] = atomicAdd(&cnt[UKEY0 + uidx[i - NE]], 1);
    }
}

__global__ void k_scan1(const int* __restrict__ in, int* __restrict__ excl,
                        int* __restrict__ bsum, int n) {
    __shared__ int s[SCAN_B];
    int tid = threadIdx.x, gid = blockIdx.x * SCAN_B + tid;
    int v = (gid < n) ? in[gid] : 0;
    s[tid] = v; __syncthreads();
    for (int off = 1; off < SCAN_B; off <<= 1) {
        int t = 0;
        if (tid >= off) t = s[tid - off];
        __syncthreads();
        s[tid] += t;
        __syncthreads();
    }
    if (gid < n) excl[gid] = s[tid] - v;
    if (tid == SCAN_B - 1) bsum[blockIdx.x] = s[tid];
}

// merged scan2+scan3: each block tree-reduces its own prefix of raw block sums.
__global__ void k_scan23(const int* __restrict__ excl, const int* __restrict__ bsum,
                         const int* __restrict__ cnt, int* __restrict__ rp,
                         int n, int nb) {
    __shared__ int s[SCAN_B];
    int tid = threadIdx.x;
    int v = (tid < nb && tid < (int)blockIdx.x) ? bsum[tid] : 0;
    s[tid] = v;
    __syncthreads();
    for (int off = SCAN_B / 2; off > 0; off >>= 1) {
        if (tid < off) s[tid] += s[tid + off];
        __syncthreads();
    }
    int prefix = s[0];
    int gid = blockIdx.x * SCAN_B + tid;
    if (gid < n) {
        int val = excl[gid] + prefix;
        rp[gid] = val;
        if (gid == n - 1) rp[n] = val + cnt[gid];
    }
}

// atomic-free scatter: pos = rp[key] + precomputed rank
__global__ void k_scatter_all(const int* __restrict__ head, const int* __restrict__ tail,
                              const int* __restrict__ etype,
                              const float* __restrict__ rw, const float* __restrict__ lat,
                              const int* __restrict__ uidx, const int* __restrict__ iidx,
                              const int* __restrict__ rp, const int* __restrict__ rank,
                              int* __restrict__ sorted) {
    __shared__ int sremap[NREL1];
    block_remap(rw, lat, sremap);
    int i = blockIdx.x * blockDim.x + threadIdx.x;
    if (i < NE) {
        int key = head[i] * 3 + sremap[etype[i] - 1];
        sorted[rp[key] + rank[i]] = tail[i];
    } else if (i < NTE) {
        int j = i - NE;
        sorted[rp[UKEY0 + uidx[j]] + rank[i]] = iidx[j];
    }
}

// ---------- degree-sort permutation via block-local counting sort ----------
__device__ __forceinline__ int perm_bucket(const int* __restrict__ rp, int i) {
    if (i < N_ENT) {
        int d = rp[i * 3 + 3] - rp[i * 3];
        return (d < NBUCK) ? d : (NBUCK - 1);
    }
    int u = i - N_ENT;
    int d = rp[UKEY0 + u + 1] - rp[UKEY0 + u];
    return NBUCK + ((d < NBUCK) ? d : (NBUCK - 1));
}

// stage 1: per-block LDS histogram -> bh[bucket*NPB + block]
__global__ void k_histL(const int* __restrict__ rp, int* __restrict__ bh) {
    __shared__ int h[2 * NBUCK];
    int t = threadIdx.x;
    if (t < 2 * NBUCK) h[t] = 0;
    __syncthreads();
    int i = blockIdx.x * 256 + t;
    if (i < NPERM) atomicAdd(&h[perm_bucket(rp, i)], 1);
    __syncthreads();
    if (t < 2 * NBUCK) bh[t * NPB + blockIdx.x] = h[t];
}

// stage 2: one workgroup per bucket; exclusive scan of bh[b][0..NPB) + total
__global__ void k_histscan(int* __restrict__ bh, int* __restrict__ bt) {
    __shared__ int s[SCAN_B];
    int b = blockIdx.x, t = threadIdx.x;
    int base = b * NPB;
    int i0 = 2 * t, i1 = 2 * t + 1;
    int a0 = (i0 < NPB) ? bh[base + i0] : 0;
    int a1 = (i1 < NPB) ? bh[base + i1] : 0;
    int pair = a0 + a1;
    s[t] = pair; __syncthreads();
    for (int off = 1; off < SCAN_B; off <<= 1) {
        int v = 0;
        if (t >= off) v = s[t - off];
        __syncthreads();
        s[t] += v;
        __syncthreads();
    }
    int exclPair = s[t] - pair;
    if (i0 < NPB) bh[base + i0] = exclPair;
    if (i1 < NPB) bh[base + i1] = exclPair + a0;
    if (t == SCAN_B - 1) bt[b] = s[t];
}

// stage 3 (folded): scatter; each block locally scans bucket totals first.
__global__ void k_permb(const int* __restrict__ rp, const int* __restrict__ bh,
                        const int* __restrict__ bt,
                        int* __restrict__ permE, int* __restrict__ permU) {
    __shared__ int sb[2 * NBUCK];
    __shared__ int cur[2 * NBUCK];
    int t = threadIdx.x;
    int v0 = 0;
    if (t < 2 * NBUCK) { v0 = bt[t]; sb[t] = v0; cur[t] = 0; }
    __syncthreads();
    for (int off = 1; off < NBUCK; off <<= 1) {
        int x = 0;
        if (t < 2 * NBUCK && t >= off && ((t - off) >> 6) == (t >> 6)) x = sb[t - off];
        __syncthreads();
        if (t < 2 * NBUCK) sb[t] += x;
        __syncthreads();
    }
    if (t < 2 * NBUCK) sb[t] -= v0;          // exclusive base within E/U half
    __syncthreads();
    int i = blockIdx.x * 256 + t;
    if (i < NPERM) {
        int b = perm_bucket(rp, i);
        int l = atomicAdd(&cur[b], 1);
        int pos = sb[b] + bh[b * NPB + blockIdx.x] + l;
        if (i < N_ENT) permE[pos] = i;
        else permU[pos] = i - N_ENT;
    }
}

// ---------- merged per-hop LWS: per-virt sequential entity path + user path ----------
#define NBLK_E (N_ENT / 16)   // 12500
#define NBLK_U (N_USR / 16)   // 6250

__global__ __launch_bounds__(256, 5) void k_hop(
    const float* __restrict__ ent, const float* __restrict__ usr,
    const int* __restrict__ rp, const int* __restrict__ sorted,
    const int* __restrict__ permE, const int* __restrict__ permU,
    const float* __restrict__ aw, int hop,
    float* __restrict__ ent_next, float* __restrict__ usr_next,
    int do_store, int first,
    float* __restrict__ outE, float* __restrict__ outU)
{
    int lane = threadIdx.x & 15;
    const float4* entv = (const float4*)ent;

    if (blockIdx.x < NBLK_E) {
        // ================= entity path: 3 independent per-virt LWS =================
        // degree-sorted order: the wave's 4 groups have near-equal degrees.
        int g = permE[blockIdx.x * 16 + (threadIdx.x >> 4)];
        float4 eh = entv[g * 16 + lane];
        float4 agg = f4_zero();

        // softmax(agg_w[hop]) inline
        float a0 = aw[hop * 3 + 0], a1 = aw[hop * 3 + 1], a2 = aw[hop * 3 + 2];
        float m = fmaxf(a0, fmaxf(a1, a2));
        float e0 = expf(a0 - m), e1 = expf(a1 - m), e2 = expf(a2 - m);
        float esum = e0 + e1 + e2;
        float w0 = e0 / esum, w1 = e1 / esum, w2 = e2 / esum;

        // hoisted index prefetch for all 3 virts (overlap 2-level chase);
        // lane-distributed headers + __shfl broadcast (proven faster than
        // per-r uniform loads — R3/R10 both confirmed; do not revisit).
        int b3 = g * 3;
        int s0 = rp[b3], s1 = rp[b3 + 1], s2 = rp[b3 + 2], s3 = rp[b3 + 3];
        int dg0 = s1 - s0, dg1 = s2 - s1, dg2 = s3 - s2;
        int myp0 = (lane < dg0) ? sorted[s0 + lane] : 0;
        int myp1 = (lane < dg1) ? sorted[s1 + lane] : 0;
        int myp2 = (lane < dg2) ? sorted[s2 + lane] : 0;

        #pragma unroll
        for (int v = 0; v < NVIRT; v++) {
            int s   = (v == 0) ? s0   : (v == 1) ? s1   : s2;
            int deg = (v == 0) ? dg0  : (v == 1) ? dg1  : dg2;
            int myp = (v == 0) ? myp0 : (v == 1) ? myp1 : myp2;
            float w = (v == 0) ? w0   : (v == 1) ? w1   : w2;
            float inv = 1.f / fmaxf((float)deg, 1.f);

            float4 xc[RE];
            // ---- iter 0 (+ cache fill)
            float4 acc = f4_zero();
            #pragma unroll
            for (int r = 0; r < RE; r++) {
                if (r < deg) {
                    int p = __shfl(myp, r, 16);
                    float4 x = entv[p * 16 + lane];
                    xc[r] = x;
                    acc = f4_add(acc, x);
                }
            }
            for (int r = RE; r < deg; r++) {
                int p = (r < 16) ? __shfl(myp, r, 16) : sorted[s + r];
                acc = f4_add(acc, entv[p * 16 + lane]);
            }
            float4 u = f4_scale(inv, acc);
            float sq = red16(f4_dot(u, u));
            float4 u1 = f4_add(squash4(u, sq), eh);

            // ---- iter 1: d1 = dot(u1,x); cached rows keep d1 in registers
            float4 acc1 = f4_zero();
            float d1c[RE];
            float d1me = 0.f;
            #pragma unroll
            for (int r = 0; r < RE; r++) {
                if (r < deg) {
                    float4 x = xc[r];
                    float d1 = red16(f4_dot(u1, x));
                    d1c[r] = d1;
                    acc1 = f4_fma(d1, x, acc1);
                }
            }
            for (int r = RE; r < deg; r++) {
                int p = (r < 16) ? __shfl(myp, r, 16) : sorted[s + r];
                float4 x = entv[p * 16 + lane];
                float d1 = red16(f4_dot(u1, x));
                if (lane == r) d1me = d1;      // only lanes 0..15, so only r<16 captured
                acc1 = f4_fma(d1, x, acc1);
            }
            u = f4_scale(inv, acc1);
            sq = red16(f4_dot(u, u));
            float4 u2 = f4_add(squash4(u, sq), eh);

            // ---- iter 2: scale = d1^2 * d2
            float4 acc2 = f4_zero();
            #pragma unroll
            for (int r = 0; r < RE; r++) {
                if (r < deg) {
                    float4 x = xc[r];
                    float d2 = red16(f4_dot(u2, x));
                    float d1 = d1c[r];
                    acc2 = f4_fma(d1 * d1 * d2, x, acc2);
                }
            }
            for (int r = RE; r < deg; r++) {
                int p = (r < 16) ? __shfl(myp, r, 16) : sorted[s + r];
                float4 x = entv[p * 16 + lane];
                float d2 = red16(f4_dot(u2, x));
                float d1 = (r < 16) ? __shfl(d1me, r, 16) : red16(f4_dot(u1, x));
                acc2 = f4_fma(d1 * d1 * d2, x, acc2);
            }
            agg = f4_fma(w * inv, acc2, agg);
        }
        // Σ_v w_v*(inv_v*acc_v + eh) = agg + eh  (Σw = 1)
        agg = f4_add(agg, eh);
        float sq = red16(f4_dot(agg, agg));
        float nn = sqrtf(sq);
        float4 en = f4_scale(1.f / fmaxf(nn, EPSF), agg);
        if (do_store) ((float4*)ent_next)[g * 16 + lane] = en;
        float4* outv = (float4*)outE;
        float4 base = first ? eh : outv[g * 16 + lane];
        outv[g * 16 + lane] = f4_add(base, en);
    } else {
        // ================= user path (register-cached rows) ======
        int gu = permU[(blockIdx.x - NBLK_E) * 16 + (threadIdx.x >> 4)];
        int s = rp[UKEY0 + gu], e = rp[UKEY0 + gu + 1];
        int deg = e - s;
        const float4* usrv = (const float4*)usr;
        float4 uh = usrv[gu * 16 + lane];
        float inv = 1.f / fmaxf((float)deg, 1.f);

        int deg16 = (deg < 16) ? deg : 16;
        int myp = (lane < deg16) ? sorted[s + lane] : 0;

        float4 xc[RU];
        float4 acc = f4_zero();
        // iter 0 + cache fill
        #pragma unroll
        for (int r = 0; r < RU; r++) {
            if (r < deg) {
                int p = __shfl(myp, r, 16);
                float4 x = entv[p * 16 + lane];
                xc[r] = x;
                acc = f4_add(acc, x);
            }
        }
        for (int r = RU; r < deg; r++) {
            int p = (r < 16) ? __shfl(myp, r, 16) : sorted[s + r];
            acc = f4_add(acc, entv[p * 16 + lane]);
        }
        float4 u = f4_scale(inv, acc);
        float sq = red16(f4_dot(u, u));
        float4 u1 = f4_add(squash4(u, sq), uh);

        // iter 1: scale = dot(u1, x)
        acc = f4_zero();
        #pragma unroll
        for (int r = 0; r < RU; r++) {
            if (r < deg) {
                float4 x = xc[r];
                acc = f4_fma(red16(f4_dot(u1, x)), x, acc);
            }
        }
        for (int r = RU; r < deg; r++) {
            int p = (r < 16) ? __shfl(myp, r, 16) : sorted[s + r];
            float4 x = entv[p * 16 + lane];
            acc = f4_fma(red16(f4_dot(u1, x)), x, acc);
        }
        u = f4_scale(inv, acc);
        sq = red16(f4_dot(u, u));
        float4 u2 = f4_add(squash4(u, sq), uh);

        // iter 2: scale = dot(u2, x)
        acc = f4_zero();
        #pragma unroll
        for (int r = 0; r < RU; r++) {
            if (r < deg) {
                float4 x = xc[r];
                acc = f4_fma(red16(f4_dot(u2, x)), x, acc);
            }
        }
        for (int r = RU; r < deg; r++) {
            int p = (r < 16) ? __shfl(myp, r, 16) : sorted[s + r];
            float4 x = entv[p * 16 + lane];
            acc = f4_fma(red16(f4_dot(u2, x)), x, acc);
        }
        float4 u3 = f4_add(f4_scale(inv, acc), uh);
        sq = red16(f4_dot(u3, u3));
        float nn = sqrtf(sq);
        float4 un = f4_scale(1.f / fmaxf(nn, EPSF), u3);
        if (do_store) ((float4*)usr_next)[gu * 16 + lane] = un;
        float4* outv = (float4*)outU;
        float4 base = first ? uh : outv[gu * 16 + lane];
        outv[gu * 16 + lane] = f4_add(base, un);
    }
}

// ---------- launch ----------
extern "C" void kernel_launch(void* const* d_in, const int* in_sizes, int n_in,
                              void* d_out, int out_size, void* d_ws, size_t ws_size,
                              hipStream_t stream)
{
    const float* entity_emb = (const float*)d_in[0];
    const float* user_emb   = (const float*)d_in[1];
    const float* latent     = (const float*)d_in[2];
    const float* rel_w      = (const float*)d_in[3];
    const float* agg_w      = (const float*)d_in[4];
    const int* edge_index   = (const int*)d_in[5];
    const int* edge_type    = (const int*)d_in[6];
    const int* user_index   = (const int*)d_in[7];
    const int* item_index   = (const int*)d_in[8];
    float* out = (float*)d_out;

    char* ws = (char*)d_ws;
    size_t off = 0;
    auto alloc = [&](size_t bytes) -> void* {
        void* p = ws + off;
        off += (bytes + 255) / 256 * 256;
        return p;
    };
    float* entA  = (float*)alloc((size_t)N_ENT * DIM * 4);
    float* usrA  = (float*)alloc((size_t)N_USR * DIM * 4);
    int* cnt     = (int*)alloc((size_t)NT3 * 4);
    int* rp      = (int*)alloc((size_t)(NT3 + 1) * 4);
    int* excl    = (int*)alloc((size_t)NT3 * 4);
    int* bsum    = (int*)alloc(1024 * 4);
    int* sorted  = (int*)alloc((size_t)NTE * 4);
    int* rank    = (int*)alloc((size_t)NTE * 4);
    int* bh      = (int*)alloc((size_t)2 * NBUCK * NPB * 4);   // 600 KB
    int* bt      = (int*)alloc(2 * NBUCK * 4);
    int* permE   = (int*)alloc((size_t)N_ENT * 4);
    int* permU   = (int*)alloc((size_t)N_USR * 4);

    const int* head = edge_index;
    const int* tail = edge_index + NE;

    hipMemsetAsync(cnt, 0, (size_t)NT3 * 4, stream);

    k_count_all<<<(NTE + 255) / 256, 256, 0, stream>>>(
        head, edge_type, rel_w, latent, user_index, cnt, rank);

    int nb = (NT3 + SCAN_B - 1) / SCAN_B;   // 684 <= 1024
    k_scan1<<<nb, SCAN_B, 0, stream>>>(cnt, excl, bsum, NT3);
    k_scan23<<<nb, SCAN_B, 0, stream>>>(excl, bsum, cnt, rp, NT3, nb);

    k_scatter_all<<<(NTE + 255) / 256, 256, 0, stream>>>(
        head, tail, edge_type, rel_w, latent, user_index, item_index, rp, rank, sorted);

    // degree-sort permutation via block-local counting sort
    k_histL<<<NPB, 256, 0, stream>>>(rp, bh);
    k_histscan<<<2 * NBUCK, SCAN_B, 0, stream>>>(bh, bt);
    k_permb<<<NPB, 256, 0, stream>>>(rp, bh, bt, permE, permU);

    const float* ec = entity_emb;
    const float* uc = user_emb;
    for (int hop = 0; hop < 2; hop++) {
        int do_store = (hop == 0);
        int first = (hop == 0);
        k_hop<<<NBLK_E + NBLK_U, 256, 0, stream>>>(
            ec, uc, rp, sorted, permE, permU, agg_w, hop, entA, usrA, do_store, first,
            out, out + (size_t)N_ENT * DIM);
        ec = entA;
        uc = usrA;
    }
}